// Round 7
// baseline (526.077 us; speedup 1.0000x reference)
//
#include <hip/hip_runtime.h>
#include <hip/hip_bf16.h>
#include <math.h>

#define NFM 512   // NFMODES
#define NE  256
#define NUN 32    // NUNPAIRED
#define NM  480   // NMODES
#define NB  32    // BATCH
#define NF  288   // NE + NUN  (Ffull dim)
#define WP  16    // panel width
#define PAIRS 8   // WP/2
#define THETA 0.03125f

typedef unsigned long long ull;

// ---------------- Ja = (J - J^T)/2 ----------------
__global__ __launch_bounds__(256)
void build_ja_k(const float* __restrict__ J, float* __restrict__ Ja) {
  int t = blockIdx.x * blockDim.x + threadIdx.x;
  int stride = gridDim.x * blockDim.x;
  for (int e = t; e < NM * NM; e += stride) {
    int i = e / NM, j = e - i * NM;
    Ja[e] = 0.5f * (J[i * NM + j] - J[j * NM + i]);
  }
}

// ---------------- Tmp[b] (256x480) = Up_b @ Ja ----------
__global__ __launch_bounds__(256)
void gemm1_k(const float* __restrict__ U, const int* __restrict__ idx,
             const float* __restrict__ Ja, float* __restrict__ Tmp) {
  const int b  = blockIdx.z;
  const int m0 = blockIdx.y << 6;
  const int n0 = blockIdx.x << 6;
  const int tid = threadIdx.x;
  __shared__ float As[16][64];
  __shared__ float Bs[16][64];
  const int ar = tid >> 2, ac = (tid & 3) << 2;
  const int br = tid >> 4, bc = (tid & 15) << 2;
  const int tx = tid & 15, ty = tid >> 4;
  const float* Arow = U + (size_t)idx[b * NE + m0 + ar] * NFM + NUN;
  float acc[4][4] = {};
  for (int l0 = 0; l0 < NM; l0 += 16) {
    float4 av = *(const float4*)(Arow + l0 + ac);
    As[ac + 0][ar] = av.x; As[ac + 1][ar] = av.y;
    As[ac + 2][ar] = av.z; As[ac + 3][ar] = av.w;
    float4 bv = make_float4(0.f, 0.f, 0.f, 0.f);
    if (n0 + bc < NM) bv = *(const float4*)(Ja + (size_t)(l0 + br) * NM + n0 + bc);
    *(float4*)(&Bs[br][bc]) = bv;
    __syncthreads();
#pragma unroll
    for (int kk = 0; kk < 16; ++kk) {
      float4 a4 = *(const float4*)(&As[kk][ty << 2]);
      float4 b4 = *(const float4*)(&Bs[kk][tx << 2]);
      float a[4] = {a4.x, a4.y, a4.z, a4.w};
      float bb[4] = {b4.x, b4.y, b4.z, b4.w};
#pragma unroll
      for (int q = 0; q < 4; ++q)
#pragma unroll
        for (int p = 0; p < 4; ++p) acc[q][p] = fmaf(a[q], bb[p], acc[q][p]);
    }
    __syncthreads();
  }
  float* Tb = Tmp + (size_t)b * NE * NM;
#pragma unroll
  for (int q = 0; q < 4; ++q) {
    int r = m0 + (ty << 2) + q;
#pragma unroll
    for (int p = 0; p < 4; ++p) {
      int m = n0 + (tx << 2) + p;
      if (m < NM) Tb[(size_t)r * NM + m] = acc[q][p];
    }
  }
}

// ---------------- F[b] = Tmp[b] @ Up_b^T  -> Ffull[0:256][0:256] ------------
__global__ __launch_bounds__(256)
void gemm2_k(const float* __restrict__ U, const int* __restrict__ idx,
             const float* __restrict__ Tmp, float* __restrict__ Ff) {
  const int b  = blockIdx.z;
  const int m0 = blockIdx.y << 6;
  const int n0 = blockIdx.x << 6;
  const int tid = threadIdx.x;
  __shared__ float As[16][64];
  __shared__ float Bs[16][64];
  const int ar = tid >> 2, ac = (tid & 3) << 2;
  const int jr = tid >> 2, kc = (tid & 3) << 2;
  const int tx = tid & 15, ty = tid >> 4;
  const float* Arow = Tmp + ((size_t)b * NE + m0 + ar) * NM;
  const float* Brow = U + (size_t)idx[b * NE + n0 + jr] * NFM + NUN;
  float acc[4][4] = {};
  for (int l0 = 0; l0 < NM; l0 += 16) {
    float4 av = *(const float4*)(Arow + l0 + ac);
    As[ac + 0][ar] = av.x; As[ac + 1][ar] = av.y;
    As[ac + 2][ar] = av.z; As[ac + 3][ar] = av.w;
    float4 bv = *(const float4*)(Brow + l0 + kc);
    Bs[kc + 0][jr] = bv.x; Bs[kc + 1][jr] = bv.y;
    Bs[kc + 2][jr] = bv.z; Bs[kc + 3][jr] = bv.w;
    __syncthreads();
#pragma unroll
    for (int kk = 0; kk < 16; ++kk) {
      float4 a4 = *(const float4*)(&As[kk][ty << 2]);
      float4 b4 = *(const float4*)(&Bs[kk][tx << 2]);
      float a[4] = {a4.x, a4.y, a4.z, a4.w};
      float bb[4] = {b4.x, b4.y, b4.z, b4.w};
#pragma unroll
      for (int q = 0; q < 4; ++q)
#pragma unroll
        for (int p = 0; p < 4; ++p) acc[q][p] = fmaf(a[q], bb[p], acc[q][p]);
    }
    __syncthreads();
  }
  float* Fb = Ff + (size_t)b * NF * NF;
#pragma unroll
  for (int q = 0; q < 4; ++q) {
    int i = m0 + (ty << 2) + q;
#pragma unroll
    for (int p = 0; p < 4; ++p) {
      int j = n0 + (tx << 2) + p;
      Fb[(size_t)i * NF + j] = acc[q][p];
    }
  }
}

// ---------------- edges ---------------
__global__ __launch_bounds__(256)
void fill_edges_k(const float* __restrict__ U, const int* __restrict__ idx,
                  float* __restrict__ Ff) {
  const int b = blockIdx.x;
  const int tid = threadIdx.x;
  float* Fb = Ff + (size_t)b * NF * NF;
  const int gr = idx[b * NE + tid];
#pragma unroll 4
  for (int u = 0; u < NUN; ++u) {
    float v = U[(size_t)gr * NFM + u];
    Fb[(size_t)tid * NF + NE + u] = v;
    Fb[(size_t)(NE + u) * NF + tid] = -v;
  }
  if (tid < NUN) {
    for (int v = 0; v < NUN; ++v) Fb[(size_t)(NE + tid) * NF + NE + v] = 0.f;
  }
}

// ---------------- Pfaffian: blocked Parlett-Reid, register panel ------------
// Thread i owns panel row i in regP[16], kept CURRENT (eager rank-2 updates).
// Pairs staged as nu=-A[i][k], c=A[i][k+1]; tau = nu*invp applied by scaling.
// Common step (threshold-no-swap): 1 barrier. Swap steps: 3 barriers.
// Trailing block updated once per panel (rank-16 streaming, split nu/c reads).
__global__ __launch_bounds__(512)
void pfpanel_k(float* __restrict__ Ff, float* __restrict__ out) {
  const int b = blockIdx.x;
  float* __restrict__ A = Ff + (size_t)b * NF * NF;
  const int tid = threadIdx.x;
  __shared__ __align__(16) float s_nu[PAIRS][NF];
  __shared__ __align__(16) float s_c[PAIRS][NF];
  __shared__ __align__(16) float s_colbuf[NF];
  __shared__ float s_dumpA[WP];
  __shared__ float s_dumpB[WP];
  __shared__ float s_pivdef[2];
  __shared__ float s_invp[PAIRS];
  __shared__ ull s_red[2][8];

  float sign = 1.f, logabs = 0.f;   // thread 0 only
  float regP[WP];

  for (int k0 = 0; k0 < NF; k0 += WP) {
    const int pend = k0 + WP;

    // ---- panel load into registers (rows > k0 live) ----
    if (tid > k0 && tid < NF) {
      const float* src = A + (size_t)tid * NF + k0;
      float4 v0 = *(const float4*)(src);
      float4 v1 = *(const float4*)(src + 4);
      float4 v2 = *(const float4*)(src + 8);
      float4 v3 = *(const float4*)(src + 12);
      regP[0]=v0.x;  regP[1]=v0.y;  regP[2]=v0.z;  regP[3]=v0.w;
      regP[4]=v1.x;  regP[5]=v1.y;  regP[6]=v1.z;  regP[7]=v1.w;
      regP[8]=v2.x;  regP[9]=v2.y;  regP[10]=v2.z; regP[11]=v2.w;
      regP[12]=v3.x; regP[13]=v3.y; regP[14]=v3.z; regP[15]=v3.w;
    }

#pragma unroll
    for (int mp = 0; mp < PAIRS; ++mp) {
      const int k = k0 + 2 * mp, lc = 2 * mp, lc1 = lc + 1;
      const int par = mp & 1;

      // ---- phase 1: column values from regs, speculative stage, argmax ----
      float vk = 0.f, vk1 = 0.f;
      ull pk = 0;
      if (tid > k && tid < NF) {
        vk = regP[lc]; vk1 = regP[lc1];
        s_colbuf[tid] = vk;
        if (tid > k + 1) { s_nu[mp][tid] = -vk; s_c[mp][tid] = vk1; }
        else             { s_pivdef[par] = vk; }   // tid == k+1
        pk = ((ull)__float_as_uint(fabsf(vk)) << 32) | (ull)(NF - tid);
      }
#pragma unroll
      for (int m = 32; m > 0; m >>= 1) {
        ull o = __shfl_xor(pk, m, 64);
        if (o > pk) pk = o;
      }
      if ((tid & 63) == 0) s_red[par][tid >> 6] = pk;
      __syncthreads();                                     // B1
      ull best = s_red[par][0];
#pragma unroll
      for (int w = 1; w < 8; ++w) if (s_red[par][w] > best) best = s_red[par][w];
      const float vmax = __uint_as_float((unsigned)(best >> 32));
      const float pivdef_raw = s_pivdef[par];
      const bool doswap = fabsf(pivdef_raw) < THETA * vmax;
      const int kp = doswap ? (NF - (int)(best & 0xffffffffULL)) : (k + 1);
      const float pivot = doswap ? -s_colbuf[kp] : -pivdef_raw;
      const float invp = 1.f / pivot;
      if (tid == 0) {
        if (doswap) sign = -sign;
        sign *= (pivot > 0.f ? 1.f : (pivot < 0.f ? -1.f : 0.f));
        logabs += logf(fabsf(pivot));
        s_invp[mp] = invp;
      }

      if (!doswap) {
        // ========== common path: eager update own row, done (1 barrier) ====
        if (tid > k + 1 && tid < NF) {
          const float t_i = -vk * invp, u_i = vk1 * invp;
#pragma unroll
          for (int c = 0; c < WP; ++c)
            if (c >= lc + 2)
              regP[c] = fmaf(t_i, s_c[mp][k0 + c],
                        fmaf(-u_i, s_nu[mp][k0 + c], regP[c]));
        }
      } else {
        const bool inpanel = (kp < pend);
        const int lckp = kp - k0;
        // ---- phase 2: dumps; case C: global col/row writeback + cc precompute
        if (tid == k + 1) {
#pragma unroll
          for (int c = 0; c < WP; ++c) s_dumpA[c] = regP[c];
        }
        if (tid == kp) {
#pragma unroll
          for (int c = 0; c < WP; ++c) s_dumpB[c] = regP[c];
        }
        float ccC = 0.f;
        if (!inpanel) {
          if (tid == kp) {
            ccC = -regP[lc1];
            A[(size_t)kp * NF + kp] = 0.f;
          } else if (tid >= pend && tid < NF) {
            float gvr = A[(size_t)tid * NF + kp];
            float S = regP[lc1];
            float cc = gvr;
            for (int m = 0; m < mp; ++m) {
              float ivm = s_invp[m];
              float nu_i = s_nu[m][tid], c_i = s_c[m][tid];
              S  = S  - ivm * (nu_i * s_c[m][k + 1] - c_i * s_nu[m][k + 1]);
              cc = cc + ivm * (nu_i * s_c[m][kp]    - c_i * s_nu[m][kp]);
            }
            A[(size_t)tid * NF + kp] = S;
            A[(size_t)kp * NF + tid] = -S;
            ccC = cc;
          }
        }
        __syncthreads();                                   // B2
        // ---- phase 3: row exchange, col swap, restage, entry swaps ----
        if (tid == kp) {
#pragma unroll
          for (int c = 0; c < WP; ++c) regP[c] = s_dumpA[c];
        }
        if (inpanel && tid == k + 1) {
#pragma unroll
          for (int c = 0; c < WP; ++c) regP[c] = s_dumpB[c];
        }
        if (inpanel && tid > k + 1 && tid < NF) {
          float a_lc1 = regP[lc1], a_kp = 0.f;
#pragma unroll
          for (int c = 0; c < WP; ++c) if (c == lckp) a_kp = regP[c];
#pragma unroll
          for (int c = 0; c < WP; ++c) if (c == lckp) regP[c] = a_lc1;
          regP[lc1] = a_kp;
        }
        if (tid > k + 1 && tid < NF) {
          float vpost = (tid == kp) ? pivdef_raw : vk;
          float cc;
          if (inpanel)          cc = regP[lc1];
          else if (tid < pend)  cc = -s_dumpB[tid - k0];
          else                  cc = ccC;                  // incl. tid==kp
          s_nu[mp][tid] = -vpost; s_c[mp][tid] = cc;
          vk = vpost; vk1 = cc;                            // for eager below
        }
        if (tid >= NF && tid < NF + mp) {
          int m = tid - NF;
          float a = s_nu[m][k + 1]; s_nu[m][k + 1] = s_nu[m][kp]; s_nu[m][kp] = a;
          float c2 = s_c[m][k + 1]; s_c[m][k + 1] = s_c[m][kp];   s_c[m][kp] = c2;
        }
        __syncthreads();                                   // B3
        if (tid > k + 1 && tid < NF) {
          const float t_i = -vk * invp, u_i = vk1 * invp;
#pragma unroll
          for (int c = 0; c < WP; ++c)
            if (c >= lc + 2)
              regP[c] = fmaf(t_i, s_c[mp][k0 + c],
                        fmaf(-u_i, s_nu[mp][k0 + c], regP[c]));
        }
      }
    }

    __syncthreads();   // all pairs staged before trailing pass

    // ---- panel-end: streaming rank-16 update of trailing block ----
    if (pend < NF) {
      const int ty = tid >> 6, tx = tid & 63;
      const int nch = (NF - pend) >> 2;
      float iv[PAIRS];
#pragma unroll
      for (int m = 0; m < PAIRS; ++m) iv[m] = s_invp[m];
      for (int jb = 0; jb < nch; jb += 64) {
        const int j4 = jb + tx;
        if (j4 < nch) {
          const int j = pend + (j4 << 2);
          float4 cj[PAIRS], nj[PAIRS];
#pragma unroll
          for (int m = 0; m < PAIRS; ++m) {
            cj[m] = *(const float4*)(&s_c[m][j]);
            nj[m] = *(const float4*)(&s_nu[m][j]);
          }
          for (int i = pend + ty; i < NF; i += 8) {
            float* ap = A + (size_t)i * NF + j;
            float4 a = *(float4*)ap;
#pragma unroll
            for (int m = 0; m < PAIRS; ++m) {
              const float ti = s_nu[m][i] * iv[m];
              const float ui = s_c[m][i] * iv[m];
              a.x = fmaf(ti, cj[m].x, fmaf(-ui, nj[m].x, a.x));
              a.y = fmaf(ti, cj[m].y, fmaf(-ui, nj[m].y, a.y));
              a.z = fmaf(ti, cj[m].z, fmaf(-ui, nj[m].z, a.z));
              a.w = fmaf(ti, cj[m].w, fmaf(-ui, nj[m].w, a.w));
            }
            *(float4*)ap = a;
          }
        }
      }
    }
    __syncthreads();   // trailing writes visible to next panel load
  }

  if (tid == 0) { out[b] = sign; out[NB + b] = logabs; }
}

extern "C" void kernel_launch(void* const* d_in, const int* in_sizes, int n_in,
                              void* d_out, int out_size, void* d_ws, size_t ws_size,
                              hipStream_t stream) {
  const float* U  = (const float*)d_in[0];
  const float* J  = (const float*)d_in[1];
  const int* idx  = (const int*)d_in[2];
  float* out = (float*)d_out;
  float* ws = (float*)d_ws;

  float* Ja  = ws;                          // 480*480
  float* Tmp = Ja + (size_t)NM * NM;        // 32*256*480
  float* Ff  = Tmp + (size_t)NB * NE * NM;  // 32*288*288

  build_ja_k<<<dim3(256), dim3(256), 0, stream>>>(J, Ja);
  gemm1_k<<<dim3(8, 4, NB), dim3(256), 0, stream>>>(U, idx, Ja, Tmp);
  gemm2_k<<<dim3(4, 4, NB), dim3(256), 0, stream>>>(U, idx, Tmp, Ff);
  fill_edges_k<<<dim3(NB), dim3(256), 0, stream>>>(U, idx, Ff);
  pfpanel_k<<<dim3(NB), dim3(512), 0, stream>>>(Ff, out);
}